// Round 4
// baseline (1183.844 us; speedup 1.0000x reference)
//
#include <hip/hip_runtime.h>
#include <hip/hip_bf16.h>
#include <cstdint>
#include <cstddef>

// ---------------------------------------------------------------------------
// MCA bilinear-attention fusion on MI355X (gfx950), bf16 MFMA pipeline.
//   kconvP/kconvA: f32 weights -> bf16 in MFMA-fragment order (ws)
//   kproj : o = l2norm(X^T @ proj)           -> ws (bf16, n,h,t,dh)
//   kmatA : A = o_rgb @ atte_w               -> ws (bf16)
//   kflash: two flash passes (row/col softmax of att), no-max softmax,
//           fused gelu + residual + tanh epilogue -> d_out (f32)
//
// R1: 8-wave blocks, 128 q-rows, async global_load_lds K/V staging.
// R2: fixed V staging offsets (row stride 512B).  430us kflash.
// R3: static K0/K1/V0/V1 + 2x unroll + setprio -> REGRESSION (977us):
//     WRITE_SIZE 203MB->1.7GB = scratch spills (register pressure from
//     duplicated bodies + per-call address math + setprio fences).
// R4: keep the static-buffer alias disambiguation (the point of R3: no
//     conservative vmcnt(0) between LDS-DMA of tile i+1 and ds_reads of
//     tile i), but register-lean:
//       - staging offsets hoisted out of the loop (stage = 4 gload16 only)
//       - no setprio anywhere
//       - compute body identical to R2's (known to fit 64 VGPR + 64 AGPR)
// ---------------------------------------------------------------------------

typedef __bf16 bf16_t;
typedef bf16_t bf16x4 __attribute__((ext_vector_type(4)));
typedef bf16_t bf16x8 __attribute__((ext_vector_type(8)));
typedef float  f32x4  __attribute__((ext_vector_type(4)));

#define DEV static __device__ __forceinline__

constexpr int Tdim = 1024;   // t
constexpr int Ddim = 1024;   // d
constexpr int DH   = 256;    // d/h
constexpr int NH   = 4;      // heads
constexpr int NB   = 16;     // batch n

DEV f32x4 mm16(bf16x8 a, bf16x8 b, f32x4 c) {
  return __builtin_amdgcn_mfma_f32_16x16x32_bf16(a, b, c, 0, 0, 0);
}

DEV bf16x8 cmb(bf16x4 lo, bf16x4 hi) {
  return __builtin_shufflevector(lo, hi, 0, 1, 2, 3, 4, 5, 6, 7);
}

// Hardware transpose read from a [K][16] bf16 chunk: lane l gets k = 4g+j (lo)
// and k = 16+4g+j (hi, offset:512B) of column (l&15).  kappa_tr(g,i).
DEV void tr_pair(const bf16_t* base, int lane, bf16x4& lo, bf16x4& hi) {
  uint32_t a = (uint32_t)(uintptr_t)base + (uint32_t)(lane * 8);
  asm volatile("ds_read_b64_tr_b16 %0, %2\n\t"
               "ds_read_b64_tr_b16 %1, %2 offset:512"
               : "=v"(lo), "=v"(hi)
               : "v"(a));
}

DEV void lgkm0_fence() {
  asm volatile("s_waitcnt lgkmcnt(0)" ::: "memory");
  __builtin_amdgcn_sched_barrier(0);
}

// async global -> LDS, 16B per lane; lds dest must be wave-uniform base.
DEV void gload16(const void* g, void* l) {
  __builtin_amdgcn_global_load_lds(
      (const __attribute__((address_space(1))) uint32_t*)g,
      (__attribute__((address_space(3))) uint32_t*)l, 16, 0, 0);
}

// ---------------------------------------------------------------------------
// kconvP: rgb_proj/flow_proj f32 -> bf16 fragments in kappa_tr order.
// Wl[mod][h][kb(32)][nf(16)][g(4)][c(16)][i(8)], k = kb*32 + tr(g,i).
// 262144 threads, 8 elems each.
// ---------------------------------------------------------------------------
__global__ void kconvP(const float* __restrict__ rgbp,
                       const float* __restrict__ flowp,
                       bf16_t* __restrict__ Wl) {
  int oc = blockIdx.x * 256 + threadIdx.x;          // 0..262143
  int c = oc & 15, g = (oc >> 4) & 3, nf = (oc >> 6) & 15;
  int kb = (oc >> 10) & 31, h = (oc >> 15) & 3, mod = oc >> 17;
  const float* src = (mod ? flowp : rgbp) + (size_t)h * Ddim * DH + nf * 16 + c;
  bf16x8 v;
#pragma unroll
  for (int i = 0; i < 8; ++i) {
    int k = kb * 32 + ((i < 4) ? 4 * g + i : 12 + 4 * g + i);
    v[i] = (bf16_t)src[(size_t)k * DH];
  }
  *(bf16x8*)(Wl + (size_t)oc * 8) = v;
}

// ---------------------------------------------------------------------------
// kconvA: atte_w f32 -> bf16 fragments in kappa' (contiguous) order.
// Wa[h][kb(8)][nf(16)][g(4)][c(16)][i(8)], k = kb*32 + 8g + i.
// 32768 threads.
// ---------------------------------------------------------------------------
__global__ void kconvA(const float* __restrict__ attw, bf16_t* __restrict__ Wa) {
  int oc = blockIdx.x * 256 + threadIdx.x;          // 0..32767
  int c = oc & 15, g = (oc >> 4) & 3, nf = (oc >> 6) & 15;
  int kb = (oc >> 10) & 7, h = oc >> 13;
  const float* src = attw + (size_t)h * DH * DH + nf * 16 + c;
  bf16x8 v;
#pragma unroll
  for (int i = 0; i < 8; ++i) {
    int k = kb * 32 + 8 * g + i;
    v[i] = (bf16_t)src[(size_t)k * DH];
  }
  *(bf16x8*)(Wa + (size_t)oc * 8) = v;
}

// ---------------------------------------------------------------------------
// kproj: o = l2norm(X^T @ proj).  grid (16, 4, 32) z = nn*2+mod, block 256.
// A (X^T tile) via chunked LDS + tr-read; W fragments direct from global.
// ---------------------------------------------------------------------------
__global__ __launch_bounds__(256, 4)
void kproj(const float* __restrict__ rgb, const float* __restrict__ flow,
           const bf16_t* __restrict__ Wl,
           bf16_t* __restrict__ o_rgb, bf16_t* __restrict__ o_flow) {
  const int t0  = blockIdx.x * 64;
  const int h   = blockIdx.y;
  const int nn  = blockIdx.z >> 1;
  const int mod = blockIdx.z & 1;
  const float* X = (mod ? flow : rgb) + (size_t)nn * Ddim * Tdim + t0;
  const bf16_t* Wb = Wl + (size_t)(mod * NH + h) * 32 * 8192;
  bf16_t* O = (mod ? o_flow : o_rgb) + (size_t)(nn * NH + h) * Tdim * DH;

  __shared__ __align__(128) bf16_t Ach[4 * 512];   // [tchunk][k=32][16]
  __shared__ float sq[4][64];

  const int tid = threadIdx.x;
  const int lane = tid & 63, wv = tid >> 6;
  const int g = lane >> 4, ln = lane & 15;

  f32x4 acc[4][4] = {};   // [mi][f]: rows t0+mi*16+4g+r, cols wv*64+f*16+ln
  const int akk = tid >> 3, atoff = (tid & 7) * 8;

  for (int kb = 0; kb < 32; ++kb) {
    {  // stage A tile (column-major in X), convert to bf16, chunked
      const float* srcx = X + (size_t)(kb * 32 + akk) * Tdim + atoff;
      float4 f0 = *(const float4*)srcx;
      float4 f1 = *(const float4*)(srcx + 4);
      bf16x8 v = {(bf16_t)f0.x, (bf16_t)f0.y, (bf16_t)f0.z, (bf16_t)f0.w,
                  (bf16_t)f1.x, (bf16_t)f1.y, (bf16_t)f1.z, (bf16_t)f1.w};
      *(bf16x8*)&Ach[(atoff >> 4) * 512 + akk * 16 + (atoff & 15)] = v;
    }
    __syncthreads();

    bf16x4 alo[4], ahi[4];
#pragma unroll
    for (int mi = 0; mi < 4; ++mi) tr_pair(&Ach[mi * 512], lane, alo[mi], ahi[mi]);
    bf16x8 wf[4];
    const bf16_t* wt = Wb + (size_t)kb * 8192 + (wv * 4) * 512 + lane * 8;
#pragma unroll
    for (int f = 0; f < 4; ++f) wf[f] = *(const bf16x8*)(wt + f * 512);
    lgkm0_fence();
#pragma unroll
    for (int mi = 0; mi < 4; ++mi) {
      bf16x8 a = cmb(alo[mi], ahi[mi]);
#pragma unroll
      for (int f = 0; f < 4; ++f) acc[mi][f] = mm16(a, wf[f], acc[mi][f]);
    }
    __syncthreads();
  }

  // row L2 norms
  float inv[4][4];
#pragma unroll
  for (int mi = 0; mi < 4; ++mi)
#pragma unroll
    for (int r = 0; r < 4; ++r) {
      float s = 0.f;
#pragma unroll
      for (int f = 0; f < 4; ++f) { float v = acc[mi][f][r]; s += v * v; }
      s += __shfl_xor(s, 1); s += __shfl_xor(s, 2);
      s += __shfl_xor(s, 4); s += __shfl_xor(s, 8);
      if (ln == 0) sq[wv][mi * 16 + 4 * g + r] = s;
    }
  __syncthreads();
#pragma unroll
  for (int mi = 0; mi < 4; ++mi)
#pragma unroll
    for (int r = 0; r < 4; ++r) {
      int rl = mi * 16 + 4 * g + r;
      float s = sq[0][rl] + sq[1][rl] + sq[2][rl] + sq[3][rl];
      inv[mi][r] = 1.0f / fmaxf(sqrtf(s), 1e-12f);
    }
#pragma unroll
  for (int mi = 0; mi < 4; ++mi)
#pragma unroll
    for (int f = 0; f < 4; ++f)
#pragma unroll
      for (int r = 0; r < 4; ++r)
        O[(size_t)(t0 + mi * 16 + 4 * g + r) * DH + wv * 64 + f * 16 + ln] =
            (bf16_t)(acc[mi][f][r] * inv[mi][r]);
}

// ---------------------------------------------------------------------------
// kmatA: A = o_rgb @ atte_w.  grid (16, 4, 16), block 256.
// A tile staged once (XOR-swizzled, b128 kappa' frags); W frags from global.
// ---------------------------------------------------------------------------
__global__ __launch_bounds__(256, 4)
void kmatA(const bf16_t* __restrict__ o_rgb, const bf16_t* __restrict__ Wa,
           bf16_t* __restrict__ Aout) {
  const int t0 = blockIdx.x * 64;
  const int h  = blockIdx.y;
  const int nn = blockIdx.z;
  const bf16_t* O = o_rgb + (size_t)(nn * NH + h) * Tdim * DH;
  bf16_t* Ao = Aout + (size_t)(nn * NH + h) * Tdim * DH;

  __shared__ __align__(128) bf16_t Alds[64 * 256];  // 32KB swizzled rows

  const int tid = threadIdx.x;
  const int lane = tid & 63, wv = tid >> 6;
  const int g = lane >> 4, ln = lane & 15;

  {  // stage 32KB contiguous -> swizzled
    const char* src = (const char*)(O + (size_t)t0 * DH);
#pragma unroll
    for (int j = 0; j < 8; ++j) {
      int gc = tid + j * 256;
      int row = gc >> 5;
      *(bf16x8*)((char*)Alds + ((gc * 16) ^ ((row & 7) << 4))) =
          *(const bf16x8*)(src + gc * 16);
    }
  }
  __syncthreads();

  f32x4 acc[4][4] = {};
  for (int kb = 0; kb < 8; ++kb) {
    bf16x8 af[4];
#pragma unroll
    for (int mi = 0; mi < 4; ++mi) {
      int row = mi * 16 + ln;
      af[mi] = *(const bf16x8*)((const char*)Alds +
               ((row * 512 + kb * 64 + g * 16) ^ ((row & 7) << 4)));
    }
    bf16x8 wf[4];
    const bf16_t* wt = Wa + (size_t)(h * 8 + kb) * 8192 + (wv * 4) * 512 + lane * 8;
#pragma unroll
    for (int f = 0; f < 4; ++f) wf[f] = *(const bf16x8*)(wt + f * 512);
#pragma unroll
    for (int mi = 0; mi < 4; ++mi)
#pragma unroll
      for (int f = 0; f < 4; ++f) acc[mi][f] = mm16(af[mi], wf[f], acc[mi][f]);
  }
#pragma unroll
  for (int mi = 0; mi < 4; ++mi)
#pragma unroll
    for (int f = 0; f < 4; ++f)
#pragma unroll
      for (int r = 0; r < 4; ++r)
        Ao[(size_t)(t0 + mi * 16 + 4 * g + r) * DH + wv * 64 + f * 16 + ln] =
            (bf16_t)acc[mi][f][r];
}

// ---------------------------------------------------------------------------
// kflash: both flash passes + epilogue.  grid 1024, block 512 (8 waves).
// bid -> p = (bid&7)*16 + (bid>>6) (consecutive same-XCD blocks share p),
// qx = (bid>>3)&7; each block owns 128 q-rows.
// s-tile = 32.  Four STATIC LDS buffers (K0/K1/V0/V1) + 2x-unrolled loop so
// the LDS-DMA writes (tile i+1) and ds_reads (tile i) are compile-time
// distinct objects -> no conservative vmcnt(0) inside compute; the only
// drain is the end-of-iteration __syncthreads (after compute).
// Staging per-thread offsets hoisted (register-lean; R3 spilled).
// ---------------------------------------------------------------------------
__global__ __launch_bounds__(512, 4)
void kflash(const bf16_t* __restrict__ o_rgb, const bf16_t* __restrict__ o_flow,
            const bf16_t* __restrict__ Aw,
            const float* __restrict__ rgb, const float* __restrict__ flow,
            float* __restrict__ out) {
  const int bid = blockIdx.x;
  const int p  = (bid & 7) * 16 + (bid >> 6);   // bijective, XCD-chunked
  const int qx = (bid >> 3) & 7;
  const int nn = p >> 3, h = (p >> 1) & 3, pass = p & 1;
  const int t0 = qx * 128;
  const size_t nhoff = (size_t)(nn * NH + h) * Tdim * DH;
  const bf16_t* Qp = (pass ? o_flow : Aw) + nhoff;
  const bf16_t* Kp = (pass ? Aw : o_flow) + nhoff;
  const bf16_t* Vp = (pass ? o_flow : o_rgb) + nhoff;
  const float*  Xr = (pass ? flow : rgb) + (size_t)nn * Ddim * Tdim;
  float* Op = out + (size_t)pass * NB * Ddim * Tdim + (size_t)nn * Ddim * Tdim;

  // Four statically distinct LDS objects (alias-analysis disambiguation).
  __shared__ __align__(128) bf16_t K0[32 * 256];   // 16KB, XOR-swizzled rows
  __shared__ __align__(128) bf16_t K1[32 * 256];
  __shared__ __align__(128) bf16_t V0[32 * 256];   // 16KB, [ech(16)][k(32)][16]
  __shared__ __align__(128) bf16_t V1[32 * 256];
  __shared__ bf16_t Plds[8][16 * 36];              // per-wave P, pad->36

  const int tid = threadIdx.x;
  const int lane = tid & 63, wv = tid >> 6;
  const int g = lane >> 4, ln = lane & 15;

  // Q fragments (kappa': contiguous 16B), row = t0 + wv*16 + ln
  bf16x8 qf[8];
  {
    const bf16_t* qrow = Qp + (size_t)(t0 + wv * 16 + ln) * DH;
#pragma unroll
    for (int ks = 0; ks < 8; ++ks)
      qf[ks] = *(const bf16x8*)(qrow + ks * 32 + 8 * g);
  }

  // hoisted per-thread staging offsets (bytes).  chunk gc = tid + j*512.
  // K: linear LDS dest, pre-swizzled global source (involutive XOR of byte
  //    bits 4-6 with row bits 9-11).  V: chunked source (row stride 512B,
  //    16B chunks), linear dest.  LDS dest: wave-uniform base (+ HW lane*16).
  int ko0, ko1, vo0, vo1;
  {
    int d0 = tid * 16;
    ko0 = d0 ^ (((d0 >> 9) & 7) << 4);
    int d1 = (tid + 512) * 16;
    ko1 = d1 ^ (((d1 >> 9) & 7) << 4);
    int e0 = tid >> 6, k0 = (tid & 63) >> 1, h0 = tid & 1;
    vo0 = k0 * 512 + (e0 * 2 + h0) * 16;
    int gc1 = tid + 512;
    int e1 = gc1 >> 6, k1 = (gc1 & 63) >> 1, h1 = gc1 & 1;
    vo1 = k1 * 512 + (e1 * 2 + h1) * 16;
  }
  const int ld0 = wv * 1024, ld1 = wv * 1024 + 8192;

  auto stage = [&](bf16_t* Kb, bf16_t* Vb, int s0) {
    const char* Ks = (const char*)Kp + (size_t)s0 * 512;
    const char* Vs = (const char*)Vp + (size_t)s0 * 512;
    gload16(Ks + ko0, (char*)Kb + ld0);
    gload16(Ks + ko1, (char*)Kb + ld1);
    gload16(Vs + vo0, (char*)Vb + ld0);
    gload16(Vs + vo1, (char*)Vb + ld1);
  };

  f32x4 eacc[16] = {};
  float l_par[4] = {0.f, 0.f, 0.f, 0.f};

  // one s-tile of compute against (Kb,Vb) — identical to R2's body.
  auto compute = [&](const bf16_t* Kb, const bf16_t* Vb) {
    // S = Q K^T : 16 rows x 32 cols per wave
    f32x4 sacc[2] = {};
#pragma unroll
    for (int ks = 0; ks < 8; ++ks)
#pragma unroll
      for (int nf = 0; nf < 2; ++nf) {
        int row = nf * 16 + ln;
        const bf16_t* kp = (const bf16_t*)((const char*)Kb +
            ((row * 512 + ks * 64 + g * 16) ^ ((row & 7) << 4)));
        sacc[nf] = mm16(qf[ks], *(const bf16x8*)kp, sacc[nf]);
      }

    // P = exp(S - 8): no max tracking (S bounded by |A_row| ~ 32)
#pragma unroll
    for (int nf = 0; nf < 2; ++nf)
#pragma unroll
      for (int r = 0; r < 4; ++r) {
        float pv = __expf(sacc[nf][r] - 8.0f);
        l_par[r] += pv;
        Plds[wv][(4 * g + r) * 36 + nf * 16 + ln] = (bf16_t)pv;
      }

    // E += P @ V  (P via kappa_tr row reads; V via tr-read)
    const bf16_t* pp = &Plds[wv][ln * 36 + 4 * g];
    bf16x8 pa = cmb(*(const bf16x4*)pp, *(const bf16x4*)(pp + 16));
#pragma unroll
    for (int nb4 = 0; nb4 < 4; ++nb4) {
      bf16x4 vlo[4], vhi[4];
#pragma unroll
      for (int j = 0; j < 4; ++j)
        tr_pair(&Vb[(nb4 * 4 + j) * 512], lane, vlo[j], vhi[j]);
      lgkm0_fence();
#pragma unroll
      for (int j = 0; j < 4; ++j)
        eacc[nb4 * 4 + j] = mm16(pa, cmb(vlo[j], vhi[j]), eacc[nb4 * 4 + j]);
    }
  };

  stage(K0, V0, 0);
  __syncthreads();           // vmcnt(0) drain + barrier: tile 0 visible

  for (int s0 = 0; s0 < Tdim; s0 += 64) {
    stage(K1, V1, s0 + 32);                    // async, flies under compute
    compute(K0, V0);
    __syncthreads();                           // drains K1/V1 loads
    if (s0 + 64 < Tdim) stage(K0, V0, s0 + 64);
    compute(K1, V1);
    __syncthreads();                           // drains K0/V0 loads
  }

  // epilogue: reduce l, normalize, exact gelu, residual, tanh
  float invl[4];
#pragma unroll
  for (int r = 0; r < 4; ++r) {
    float l = l_par[r];
    l += __shfl_xor(l, 1); l += __shfl_xor(l, 2);
    l += __shfl_xor(l, 4); l += __shfl_xor(l, 8);
    invl[r] = 1.0f / l;
  }
#pragma unroll
  for (int nb = 0; nb < 16; ++nb)
#pragma unroll
    for (int r = 0; r < 4; ++r) {
      float e = eacc[nb][r] * invl[r];
      float ge = 0.5f * e * (1.0f + erff(e * 0.70710678118f));
      int trow = t0 + wv * 16 + 4 * g + r;
      int col = h * 256 + nb * 16 + ln;
      size_t idx = (size_t)trow * Tdim + col;
      Op[idx] = tanhf(ge + Xr[idx]);
    }
}

// ---------------------------------------------------------------------------
extern "C" void kernel_launch(void* const* d_in, const int* in_sizes, int n_in,
                              void* d_out, int out_size, void* d_ws, size_t ws_size,
                              hipStream_t stream) {
  const float* rgb   = (const float*)d_in[0];
  const float* flow  = (const float*)d_in[1];
  const float* rgbp  = (const float*)d_in[2];
  const float* flowp = (const float*)d_in[3];
  const float* attw  = (const float*)d_in[4];
  float* out = (float*)d_out;

  const size_t OSZ = (size_t)NB * NH * Tdim * DH;   // 16.7M bf16
  bf16_t* o_rgb  = (bf16_t*)d_ws;                   // 32 MB
  bf16_t* o_flow = o_rgb + OSZ;                     // 32 MB
  bf16_t* Aw     = o_flow + OSZ;                    // 32 MB
  bf16_t* Wl     = Aw + OSZ;                        // 4 MB (2M elems)
  bf16_t* Wa     = Wl + (size_t)2 * NH * 32 * 8192; // 0.5 MB

  kconvP<<<1024, 256, 0, stream>>>(rgbp, flowp, Wl);
  kconvA<<<128, 256, 0, stream>>>(attw, Wa);
  kproj<<<dim3(16, 4, 32), 256, 0, stream>>>(rgb, flow, Wl, o_rgb, o_flow);
  kmatA<<<dim3(16, 4, 16), 256, 0, stream>>>(o_rgb, Wa, Aw);
  kflash<<<1024, 512, 0, stream>>>(o_rgb, o_flow, Aw, rgb, flow, out);
}

// Round 5
// 473.282 us; speedup vs baseline: 2.5014x; 2.5014x over previous
//
#include <hip/hip_runtime.h>
#include <hip/hip_bf16.h>
#include <cstdint>
#include <cstddef>

// ---------------------------------------------------------------------------
// MCA bilinear-attention fusion on MI355X (gfx950), bf16 MFMA pipeline.
//   kconvP/kconvA: f32 weights -> bf16 in MFMA-fragment order (ws)
//   kproj : o = l2norm(X^T @ proj)           -> ws (bf16, n,h,t,dh)
//   kmatA : A = o_rgb @ atte_w               -> ws (bf16)
//   kflash: two flash passes (row/col softmax of att), no-max softmax,
//           fused gelu + residual + tanh epilogue -> d_out (f32)
//
// R2: 8-wave blocks, async global_load_lds K/V staging, 430us kflash.
// R3/R4: restructures spilled (launch_bounds(512,4) = 128-reg budget; body
//        needed more -> 1.9GB scratch round-trip).  REVERTED.
// R5: kflash is LDS-BANDWIDTH-bound (each R2 wave read the full 16KB K tile
//     and 16KB V tile per s-tile; ~300KB LDS traffic per block-tile; conflict
//     counter saturated at 2^24).  Fix: 32 q-rows per wave via TWO row-groups
//     sharing every K/V fragment -> LDS bytes per MFMA halved.
//       - block 256 thr / 4 waves, 128 q-rows (grid/p-mapping unchanged)
//       - each LDS K-frag / V-tr-frag feeds 2 MFMAs (rg=0,1)
//       - regs ~235 (eacc 128 + qf 64 + temps) -> launch_bounds(256,2),
//         2 blocks/CU (LDS 74.75KB), no spill by construction
//       - staging/swizzle/softmax/epilogue patterns byte-identical to R2
// ---------------------------------------------------------------------------

typedef __bf16 bf16_t;
typedef bf16_t bf16x4 __attribute__((ext_vector_type(4)));
typedef bf16_t bf16x8 __attribute__((ext_vector_type(8)));
typedef float  f32x4  __attribute__((ext_vector_type(4)));

#define DEV static __device__ __forceinline__

constexpr int Tdim = 1024;   // t
constexpr int Ddim = 1024;   // d
constexpr int DH   = 256;    // d/h
constexpr int NH   = 4;      // heads
constexpr int NB   = 16;     // batch n

DEV f32x4 mm16(bf16x8 a, bf16x8 b, f32x4 c) {
  return __builtin_amdgcn_mfma_f32_16x16x32_bf16(a, b, c, 0, 0, 0);
}

DEV bf16x8 cmb(bf16x4 lo, bf16x4 hi) {
  return __builtin_shufflevector(lo, hi, 0, 1, 2, 3, 4, 5, 6, 7);
}

// Hardware transpose read from a [K][16] bf16 chunk: lane l gets k = 4g+j (lo)
// and k = 16+4g+j (hi, offset:512B) of column (l&15).  kappa_tr(g,i).
DEV void tr_pair(const bf16_t* base, int lane, bf16x4& lo, bf16x4& hi) {
  uint32_t a = (uint32_t)(uintptr_t)base + (uint32_t)(lane * 8);
  asm volatile("ds_read_b64_tr_b16 %0, %2\n\t"
               "ds_read_b64_tr_b16 %1, %2 offset:512"
               : "=v"(lo), "=v"(hi)
               : "v"(a));
}

DEV void lgkm0_fence() {
  asm volatile("s_waitcnt lgkmcnt(0)" ::: "memory");
  __builtin_amdgcn_sched_barrier(0);
}

// async global -> LDS, 16B per lane; lds dest must be wave-uniform base.
DEV void gload16(const void* g, void* l) {
  __builtin_amdgcn_global_load_lds(
      (const __attribute__((address_space(1))) uint32_t*)g,
      (__attribute__((address_space(3))) uint32_t*)l, 16, 0, 0);
}

// ---------------------------------------------------------------------------
// kconvP: rgb_proj/flow_proj f32 -> bf16 fragments in kappa_tr order.
// Wl[mod][h][kb(32)][nf(16)][g(4)][c(16)][i(8)], k = kb*32 + tr(g,i).
// 262144 threads, 8 elems each.
// ---------------------------------------------------------------------------
__global__ void kconvP(const float* __restrict__ rgbp,
                       const float* __restrict__ flowp,
                       bf16_t* __restrict__ Wl) {
  int oc = blockIdx.x * 256 + threadIdx.x;          // 0..262143
  int c = oc & 15, g = (oc >> 4) & 3, nf = (oc >> 6) & 15;
  int kb = (oc >> 10) & 31, h = (oc >> 15) & 3, mod = oc >> 17;
  const float* src = (mod ? flowp : rgbp) + (size_t)h * Ddim * DH + nf * 16 + c;
  bf16x8 v;
#pragma unroll
  for (int i = 0; i < 8; ++i) {
    int k = kb * 32 + ((i < 4) ? 4 * g + i : 12 + 4 * g + i);
    v[i] = (bf16_t)src[(size_t)k * DH];
  }
  *(bf16x8*)(Wl + (size_t)oc * 8) = v;
}

// ---------------------------------------------------------------------------
// kconvA: atte_w f32 -> bf16 fragments in kappa' (contiguous) order.
// Wa[h][kb(8)][nf(16)][g(4)][c(16)][i(8)], k = kb*32 + 8g + i.
// 32768 threads.
// ---------------------------------------------------------------------------
__global__ void kconvA(const float* __restrict__ attw, bf16_t* __restrict__ Wa) {
  int oc = blockIdx.x * 256 + threadIdx.x;          // 0..32767
  int c = oc & 15, g = (oc >> 4) & 3, nf = (oc >> 6) & 15;
  int kb = (oc >> 10) & 7, h = oc >> 13;
  const float* src = attw + (size_t)h * DH * DH + nf * 16 + c;
  bf16x8 v;
#pragma unroll
  for (int i = 0; i < 8; ++i) {
    int k = kb * 32 + 8 * g + i;
    v[i] = (bf16_t)src[(size_t)k * DH];
  }
  *(bf16x8*)(Wa + (size_t)oc * 8) = v;
}

// ---------------------------------------------------------------------------
// kproj: o = l2norm(X^T @ proj).  grid (16, 4, 32) z = nn*2+mod, block 256.
// A (X^T tile) via chunked LDS + tr-read; W fragments direct from global.
// ---------------------------------------------------------------------------
__global__ __launch_bounds__(256, 4)
void kproj(const float* __restrict__ rgb, const float* __restrict__ flow,
           const bf16_t* __restrict__ Wl,
           bf16_t* __restrict__ o_rgb, bf16_t* __restrict__ o_flow) {
  const int t0  = blockIdx.x * 64;
  const int h   = blockIdx.y;
  const int nn  = blockIdx.z >> 1;
  const int mod = blockIdx.z & 1;
  const float* X = (mod ? flow : rgb) + (size_t)nn * Ddim * Tdim + t0;
  const bf16_t* Wb = Wl + (size_t)(mod * NH + h) * 32 * 8192;
  bf16_t* O = (mod ? o_flow : o_rgb) + (size_t)(nn * NH + h) * Tdim * DH;

  __shared__ __align__(128) bf16_t Ach[4 * 512];   // [tchunk][k=32][16]
  __shared__ float sq[4][64];

  const int tid = threadIdx.x;
  const int lane = tid & 63, wv = tid >> 6;
  const int g = lane >> 4, ln = lane & 15;

  f32x4 acc[4][4] = {};   // [mi][f]: rows t0+mi*16+4g+r, cols wv*64+f*16+ln
  const int akk = tid >> 3, atoff = (tid & 7) * 8;

  for (int kb = 0; kb < 32; ++kb) {
    {  // stage A tile (column-major in X), convert to bf16, chunked
      const float* srcx = X + (size_t)(kb * 32 + akk) * Tdim + atoff;
      float4 f0 = *(const float4*)srcx;
      float4 f1 = *(const float4*)(srcx + 4);
      bf16x8 v = {(bf16_t)f0.x, (bf16_t)f0.y, (bf16_t)f0.z, (bf16_t)f0.w,
                  (bf16_t)f1.x, (bf16_t)f1.y, (bf16_t)f1.z, (bf16_t)f1.w};
      *(bf16x8*)&Ach[(atoff >> 4) * 512 + akk * 16 + (atoff & 15)] = v;
    }
    __syncthreads();

    bf16x4 alo[4], ahi[4];
#pragma unroll
    for (int mi = 0; mi < 4; ++mi) tr_pair(&Ach[mi * 512], lane, alo[mi], ahi[mi]);
    bf16x8 wf[4];
    const bf16_t* wt = Wb + (size_t)kb * 8192 + (wv * 4) * 512 + lane * 8;
#pragma unroll
    for (int f = 0; f < 4; ++f) wf[f] = *(const bf16x8*)(wt + f * 512);
    lgkm0_fence();
#pragma unroll
    for (int mi = 0; mi < 4; ++mi) {
      bf16x8 a = cmb(alo[mi], ahi[mi]);
#pragma unroll
      for (int f = 0; f < 4; ++f) acc[mi][f] = mm16(a, wf[f], acc[mi][f]);
    }
    __syncthreads();
  }

  // row L2 norms
  float inv[4][4];
#pragma unroll
  for (int mi = 0; mi < 4; ++mi)
#pragma unroll
    for (int r = 0; r < 4; ++r) {
      float s = 0.f;
#pragma unroll
      for (int f = 0; f < 4; ++f) { float v = acc[mi][f][r]; s += v * v; }
      s += __shfl_xor(s, 1); s += __shfl_xor(s, 2);
      s += __shfl_xor(s, 4); s += __shfl_xor(s, 8);
      if (ln == 0) sq[wv][mi * 16 + 4 * g + r] = s;
    }
  __syncthreads();
#pragma unroll
  for (int mi = 0; mi < 4; ++mi)
#pragma unroll
    for (int r = 0; r < 4; ++r) {
      int rl = mi * 16 + 4 * g + r;
      float s = sq[0][rl] + sq[1][rl] + sq[2][rl] + sq[3][rl];
      inv[mi][r] = 1.0f / fmaxf(sqrtf(s), 1e-12f);
    }
#pragma unroll
  for (int mi = 0; mi < 4; ++mi)
#pragma unroll
    for (int f = 0; f < 4; ++f)
#pragma unroll
      for (int r = 0; r < 4; ++r)
        O[(size_t)(t0 + mi * 16 + 4 * g + r) * DH + wv * 64 + f * 16 + ln] =
            (bf16_t)(acc[mi][f][r] * inv[mi][r]);
}

// ---------------------------------------------------------------------------
// kmatA: A = o_rgb @ atte_w.  grid (16, 4, 16), block 256.
// A tile staged once (XOR-swizzled, b128 kappa' frags); W frags from global.
// ---------------------------------------------------------------------------
__global__ __launch_bounds__(256, 4)
void kmatA(const bf16_t* __restrict__ o_rgb, const bf16_t* __restrict__ Wa,
           bf16_t* __restrict__ Aout) {
  const int t0 = blockIdx.x * 64;
  const int h  = blockIdx.y;
  const int nn = blockIdx.z;
  const bf16_t* O = o_rgb + (size_t)(nn * NH + h) * Tdim * DH;
  bf16_t* Ao = Aout + (size_t)(nn * NH + h) * Tdim * DH;

  __shared__ __align__(128) bf16_t Alds[64 * 256];  // 32KB swizzled rows

  const int tid = threadIdx.x;
  const int lane = tid & 63, wv = tid >> 6;
  const int g = lane >> 4, ln = lane & 15;

  {  // stage 32KB contiguous -> swizzled
    const char* src = (const char*)(O + (size_t)t0 * DH);
#pragma unroll
    for (int j = 0; j < 8; ++j) {
      int gc = tid + j * 256;
      int row = gc >> 5;
      *(bf16x8*)((char*)Alds + ((gc * 16) ^ ((row & 7) << 4))) =
          *(const bf16x8*)(src + gc * 16);
    }
  }
  __syncthreads();

  f32x4 acc[4][4] = {};
  for (int kb = 0; kb < 8; ++kb) {
    bf16x8 af[4];
#pragma unroll
    for (int mi = 0; mi < 4; ++mi) {
      int row = mi * 16 + ln;
      af[mi] = *(const bf16x8*)((const char*)Alds +
               ((row * 512 + kb * 64 + g * 16) ^ ((row & 7) << 4)));
    }
    bf16x8 wf[4];
    const bf16_t* wt = Wa + (size_t)(h * 8 + kb) * 8192 + (wv * 4) * 512 + lane * 8;
#pragma unroll
    for (int f = 0; f < 4; ++f) wf[f] = *(const bf16x8*)(wt + f * 512);
#pragma unroll
    for (int mi = 0; mi < 4; ++mi)
#pragma unroll
      for (int f = 0; f < 4; ++f) acc[mi][f] = mm16(af[mi], wf[f], acc[mi][f]);
  }
#pragma unroll
  for (int mi = 0; mi < 4; ++mi)
#pragma unroll
    for (int f = 0; f < 4; ++f)
#pragma unroll
      for (int r = 0; r < 4; ++r)
        Ao[(size_t)(t0 + mi * 16 + 4 * g + r) * DH + wv * 64 + f * 16 + ln] =
            (bf16_t)acc[mi][f][r];
}

// ---------------------------------------------------------------------------
// kflash: both flash passes + epilogue.  grid 1024, block 256 (4 waves).
// bid -> p = (bid&7)*16 + (bid>>6) (consecutive same-XCD blocks share p),
// qx = (bid>>3)&7; each block owns 128 q-rows (32 per wave, 2 row-groups).
// s-tile = 32, K/V double-buffered via global_load_lds; each K B-frag and
// V tr-frag read from LDS feeds BOTH row-groups (halves LDS traffic/MFMA).
// No-max softmax: P = exp(S-8), l accumulated per-lane.
// ---------------------------------------------------------------------------
__global__ __launch_bounds__(256, 2)
void kflash(const bf16_t* __restrict__ o_rgb, const bf16_t* __restrict__ o_flow,
            const bf16_t* __restrict__ Aw,
            const float* __restrict__ rgb, const float* __restrict__ flow,
            float* __restrict__ out) {
  const int bid = blockIdx.x;
  const int p  = (bid & 7) * 16 + (bid >> 6);   // bijective, XCD-chunked
  const int qx = (bid >> 3) & 7;
  const int nn = p >> 3, h = (p >> 1) & 3, pass = p & 1;
  const int t0 = qx * 128;
  const size_t nhoff = (size_t)(nn * NH + h) * Tdim * DH;
  const bf16_t* Qp = (pass ? o_flow : Aw) + nhoff;
  const bf16_t* Kp = (pass ? Aw : o_flow) + nhoff;
  const bf16_t* Vp = (pass ? o_flow : o_rgb) + nhoff;
  const float*  Xr = (pass ? flow : rgb) + (size_t)nn * Ddim * Tdim;
  float* Op = out + (size_t)pass * NB * Ddim * Tdim + (size_t)nn * Ddim * Tdim;

  __shared__ __align__(128) bf16_t Klds[2][32 * 256];  // 2x16KB, XOR-swizzled
  __shared__ __align__(128) bf16_t Vch [2][32 * 256];  // 2x16KB, [ech][k(32)][16]
  __shared__ bf16_t Plds[4][32 * 36];                  // per-wave P (32 rows)

  const int tid = threadIdx.x;
  const int lane = tid & 63, wv = tid >> 6;            // wv 0..3
  const int g = lane >> 4, ln = lane & 15;

  // Q fragments (kappa': contiguous 16B), rows t0 + wv*32 + rg*16 + ln
  bf16x8 qf[2][8];
#pragma unroll
  for (int rg = 0; rg < 2; ++rg) {
    const bf16_t* qrow = Qp + (size_t)(t0 + wv * 32 + rg * 16 + ln) * DH;
#pragma unroll
    for (int ks = 0; ks < 8; ++ks)
      qf[rg][ks] = *(const bf16x8*)(qrow + ks * 32 + 8 * g);
  }

  // async stage of one 32-row K/V tile into buffer b (8 chunks per thread).
  // K: linear LDS dest, pre-swizzled global source (involutive XOR of byte
  //    bits 4-6 with row bits 9-11).  V: chunked source (row stride 512B,
  //    16B chunks), linear dest.  LDS dest: wave-uniform base + lane*16.
  auto stage = [&](int b, int s0) {
    const char* Ks = (const char*)Kp + (size_t)s0 * 512;
    const char* Vs = (const char*)Vp + (size_t)s0 * 512;
    char* Kd = (char*)&Klds[b][0] + wv * 1024;
    char* Vd = (char*)&Vch[b][0] + wv * 1024;
#pragma unroll
    for (int j = 0; j < 4; ++j) {
      int gc = j * 256 + tid;                    // 16B chunk index, 0..1023
      int d  = gc * 16;
      gload16(Ks + (d ^ (((d >> 9) & 7) << 4)), Kd + j * 4096);
      int ech = gc >> 6, kk = (gc & 63) >> 1, half = gc & 1;
      gload16(Vs + kk * 512 + (ech * 2 + half) * 16, Vd + j * 4096);
    }
  };

  f32x4 eacc[2][16] = {};
  float l_par[2][4] = {};

  stage(0, 0);
  __syncthreads();           // vmcnt(0) drain + barrier: tile 0 visible

  int cur = 0;
  for (int s0 = 0; s0 < Tdim; s0 += 32) {
    if (s0 + 32 < Tdim) stage(cur ^ 1, s0 + 32);   // async, flies under compute

    // S = Q K^T : 32 rows x 32 cols per wave; each K frag feeds both rg
    f32x4 sacc[2][2] = {};
#pragma unroll
    for (int ks = 0; ks < 8; ++ks)
#pragma unroll
      for (int nf = 0; nf < 2; ++nf) {
        int row = nf * 16 + ln;
        bf16x8 kf = *(const bf16x8*)((const char*)&Klds[cur][0] +
            ((row * 512 + ks * 64 + g * 16) ^ ((row & 7) << 4)));
        sacc[0][nf] = mm16(qf[0][ks], kf, sacc[0][nf]);
        sacc[1][nf] = mm16(qf[1][ks], kf, sacc[1][nf]);
      }

    // P = exp(S - 8): no max tracking (S bounded by |A_row| ~ 32)
#pragma unroll
    for (int rg = 0; rg < 2; ++rg)
#pragma unroll
      for (int nf = 0; nf < 2; ++nf)
#pragma unroll
        for (int r = 0; r < 4; ++r) {
          float pv = __expf(sacc[rg][nf][r] - 8.0f);
          l_par[rg][r] += pv;
          Plds[wv][(rg * 16 + 4 * g + r) * 36 + nf * 16 + ln] = (bf16_t)pv;
        }

    // E += P @ V  (P via kappa_tr row reads; V via tr-read, shared by rg)
    const bf16_t* pp0 = &Plds[wv][ln * 36 + 4 * g];
    const bf16_t* pp1 = &Plds[wv][(16 + ln) * 36 + 4 * g];
    bf16x8 pa0 = cmb(*(const bf16x4*)pp0, *(const bf16x4*)(pp0 + 16));
    bf16x8 pa1 = cmb(*(const bf16x4*)pp1, *(const bf16x4*)(pp1 + 16));
#pragma unroll
    for (int nb4 = 0; nb4 < 4; ++nb4) {
      bf16x4 vlo[4], vhi[4];
#pragma unroll
      for (int j = 0; j < 4; ++j)
        tr_pair(&Vch[cur][(nb4 * 4 + j) * 512], lane, vlo[j], vhi[j]);
      lgkm0_fence();
#pragma unroll
      for (int j = 0; j < 4; ++j) {
        bf16x8 vf = cmb(vlo[j], vhi[j]);
        eacc[0][nb4 * 4 + j] = mm16(pa0, vf, eacc[0][nb4 * 4 + j]);
        eacc[1][nb4 * 4 + j] = mm16(pa1, vf, eacc[1][nb4 * 4 + j]);
      }
    }

    __syncthreads();         // next tile landed; all waves done with cur
    cur ^= 1;
  }

  // epilogue: reduce l, normalize, exact gelu, residual, tanh
  float invl[2][4];
#pragma unroll
  for (int rg = 0; rg < 2; ++rg)
#pragma unroll
    for (int r = 0; r < 4; ++r) {
      float l = l_par[rg][r];
      l += __shfl_xor(l, 1); l += __shfl_xor(l, 2);
      l += __shfl_xor(l, 4); l += __shfl_xor(l, 8);
      invl[rg][r] = 1.0f / l;
    }
#pragma unroll
  for (int rg = 0; rg < 2; ++rg)
#pragma unroll
    for (int nb = 0; nb < 16; ++nb)
#pragma unroll
      for (int r = 0; r < 4; ++r) {
        float e = eacc[rg][nb][r] * invl[rg][r];
        float ge = 0.5f * e * (1.0f + erff(e * 0.70710678118f));
        int trow = t0 + wv * 32 + rg * 16 + 4 * g + r;
        int col = h * 256 + nb * 16 + ln;
        size_t idx = (size_t)trow * Tdim + col;
        Op[idx] = tanhf(ge + Xr[idx]);
      }
}

// ---------------------------------------------------------------------------
extern "C" void kernel_launch(void* const* d_in, const int* in_sizes, int n_in,
                              void* d_out, int out_size, void* d_ws, size_t ws_size,
                              hipStream_t stream) {
  const float* rgb   = (const float*)d_in[0];
  const float* flow  = (const float*)d_in[1];
  const float* rgbp  = (const float*)d_in[2];
  const float* flowp = (const float*)d_in[3];
  const float* attw  = (const float*)d_in[4];
  float* out = (float*)d_out;

  const size_t OSZ = (size_t)NB * NH * Tdim * DH;   // 16.7M bf16
  bf16_t* o_rgb  = (bf16_t*)d_ws;                   // 32 MB
  bf16_t* o_flow = o_rgb + OSZ;                     // 32 MB
  bf16_t* Aw     = o_flow + OSZ;                    // 32 MB
  bf16_t* Wl     = Aw + OSZ;                        // 4 MB (2M elems)
  bf16_t* Wa     = Wl + (size_t)2 * NH * 32 * 8192; // 0.5 MB

  kconvP<<<1024, 256, 0, stream>>>(rgbp, flowp, Wl);
  kconvA<<<128, 256, 0, stream>>>(attw, Wa);
  kproj<<<dim3(16, 4, 32), 256, 0, stream>>>(rgb, flow, Wl, o_rgb, o_flow);
  kmatA<<<dim3(16, 4, 16), 256, 0, stream>>>(o_rgb, Wa, Aw);
  kflash<<<1024, 256, 0, stream>>>(o_rgb, o_flow, Aw, rgb, flow, out);
}